// Round 7
// baseline (1670.536 us; speedup 1.0000x reference)
//
#include <hip/hip_runtime.h>
#include <hip/hip_cooperative_groups.h>
#include <stdint.h>

#define H 4096

typedef float v4f __attribute__((ext_vector_type(4)));
typedef long long v2l __attribute__((ext_vector_type(2)));

namespace cg = cooperative_groups;

__device__ __forceinline__ void gload16(const uint8_t* g, uint8_t* l) {
  __builtin_amdgcn_global_load_lds(
      (const __attribute__((address_space(1))) uint8_t*)g,
      (__attribute__((address_space(3))) uint8_t*)l, 16, 0, 0);
}

// permuted byte position within a 128-B k-block: orig b = ks*32 + q*8 + j
// stored at q*32 + ks*8 + j  (lane's (q,ks),(q,ks+1) frags contiguous 16B)
__device__ __forceinline__ int permpos(int kg) {
  const int kb = kg >> 7, b = kg & 127;
  const int ks = b >> 5, q = (b >> 3) & 3, j = b & 7;
  return kb * 128 + q * 32 + ks * 8 + j;
}

// ================= stage bodies (arithmetic identical to R6 kernels) ======

// weights: fp32 [k][n] -> fp8 transposed+permuted [n][perm(k)]; 6144 tiles
__device__ void conv_stage(const float* __restrict__ w0,
                           const float* __restrict__ w1,
                           const float* __restrict__ w2, uint8_t* o0,
                           uint8_t* o1, uint8_t* o2, uint8_t* smem, int bid,
                           int nb) {
  uint8_t(*t)[136] = reinterpret_cast<uint8_t(*)[136]>(smem);
  const int tid = threadIdx.x;
  const int rr = tid >> 4, cc = (tid & 15) * 4;
  for (int g = bid; g < 6144; g += nb) {
    const int z = g >> 11, rem = g & 2047;
    const int k0 = (rem >> 6) * 128, n0 = (rem & 63) * 64;
    const float* w = (z == 0) ? w0 : (z == 1 ? w1 : w2);
    uint8_t* o = (z == 0) ? o0 : (z == 1 ? o1 : o2);
#pragma unroll
    for (int j = 0; j < 8; ++j) {
      const int r = rr + j * 16;
      v4f f = *(const v4f*)(w + (size_t)(k0 + r) * H + n0 + cc);
      unsigned p = __builtin_amdgcn_cvt_pk_fp8_f32(f.x, f.y, 0, false);
      p = __builtin_amdgcn_cvt_pk_fp8_f32(f.z, f.w, p, true);
      t[cc + 0][r] = p & 0xff;
      t[cc + 1][r] = (p >> 8) & 0xff;
      t[cc + 2][r] = (p >> 16) & 0xff;
      t[cc + 3][r] = p >> 24;
    }
    __syncthreads();
#pragma unroll
    for (int i = 0; i < 2; ++i) {
      const int c = i * 256 + tid;
      const int n = c >> 3, o16 = c & 7, q = o16 >> 1, h = o16 & 1;
      long long lo = *(const long long*)&t[n][64 * h + q * 8];
      long long hi = *(const long long*)&t[n][64 * h + 32 + q * 8];
      v2l val;
      val.x = lo;
      val.y = hi;
      *(v2l*)(o + (size_t)(n0 + n) * H + k0 + o16 * 16) = val;
    }
    __syncthreads();  // LDS WAR across tiles
  }
}

// (optional relu) + rmsnorm + group-128 fp8 quant; 4096 rows grid-stride
__device__ void quant_stage(const float* in, const float* __restrict__ nw,
                            uint8_t* __restrict__ q, float* __restrict__ sxT,
                            const int relu, uint8_t* smem, int bid, int nb) {
  float* red = reinterpret_cast<float*>(smem);
  const int tid = threadIdx.x;
  for (int row = bid; row < 4096; row += nb) {
    const v4f* rp = (const v4f*)(in + (size_t)row * H);
    v4f v[4];
    float ss = 0.f;
#pragma unroll
    for (int j = 0; j < 4; ++j) {
      v4f x = rp[j * 256 + tid];
      if (relu) {
        x.x = fmaxf(x.x, 0.f); x.y = fmaxf(x.y, 0.f);
        x.z = fmaxf(x.z, 0.f); x.w = fmaxf(x.w, 0.f);
      }
      v[j] = x;
      ss += x.x * x.x + x.y * x.y + x.z * x.z + x.w * x.w;
    }
#pragma unroll
    for (int o = 32; o > 0; o >>= 1) ss += __shfl_down(ss, o);
    if ((tid & 63) == 0) red[tid >> 6] = ss;
    __syncthreads();
    ss = red[0] + red[1] + red[2] + red[3];
    const float rinv = 1.f / sqrtf(ss * (1.f / H) + 1e-6f);
#pragma unroll
    for (int j = 0; j < 4; ++j) {
      v4f nv = ((const v4f*)nw)[j * 256 + tid];
      v4f y;
      y.x = v[j].x * rinv * nv.x;
      y.y = v[j].y * rinv * nv.y;
      y.z = v[j].z * rinv * nv.z;
      y.w = v[j].w * rinv * nv.w;
      float am =
          fmaxf(fmaxf(fabsf(y.x), fabsf(y.y)), fmaxf(fabsf(y.z), fabsf(y.w)));
#pragma unroll
      for (int o = 16; o > 0; o >>= 1) am = fmaxf(am, __shfl_xor(am, o, 32));
      const float s = fmaxf(am, 1e-12f) / 448.f;  // true div: bit-exact vs ref
      unsigned p = __builtin_amdgcn_cvt_pk_fp8_f32(y.x / s, y.y / s, 0, false);
      p = __builtin_amdgcn_cvt_pk_fp8_f32(y.z / s, y.w / s, p, true);
      const int col = (j * 256 + tid) * 4;
      *(unsigned*)(q + (size_t)row * H + permpos(col)) = p;
      if ((tid & 31) == 0)
        sxT[(size_t)(j * 8 + (tid >> 5)) * 4096 + row] = s;
    }
    __syncthreads();  // red WAR across rows
  }
}

// final rmsnorm, in-place
__device__ void norm_stage(float* io, const float* __restrict__ nw,
                           uint8_t* smem, int bid, int nb) {
  float* red = reinterpret_cast<float*>(smem);
  const int tid = threadIdx.x;
  for (int row = bid; row < 4096; row += nb) {
    v4f* rp = (v4f*)(io + (size_t)row * H);
    v4f v[4];
    float ss = 0.f;
#pragma unroll
    for (int j = 0; j < 4; ++j) {
      v4f x = rp[j * 256 + tid];
      v[j] = x;
      ss += x.x * x.x + x.y * x.y + x.z * x.z + x.w * x.w;
    }
#pragma unroll
    for (int o = 32; o > 0; o >>= 1) ss += __shfl_down(ss, o);
    if ((tid & 63) == 0) red[tid >> 6] = ss;
    __syncthreads();
    ss = red[0] + red[1] + red[2] + red[3];
    const float rinv = 1.f / sqrtf(ss * (1.f / H) + 1e-6f);
#pragma unroll
    for (int j = 0; j < 4; ++j) {
      v4f nv = ((const v4f*)nw)[j * 256 + tid];
      v4f y;
      y.x = v[j].x * rinv * nv.x;
      y.y = v[j].y * rinv * nv.y;
      y.z = v[j].z * rinv * nv.z;
      y.w = v[j].w * rinv * nv.w;
      rp[j * 256 + tid] = y;
    }
    __syncthreads();  // red WAR across rows
  }
}

// block-scaled fp8 GEMM (R0 structure verbatim); 1024 tiles grid-stride
__device__ void gemm_stage(const uint8_t* __restrict__ qa,
                           const float* __restrict__ sxT,
                           const uint8_t* __restrict__ wt,
                           const float* __restrict__ ws, const float* resid,
                           float* outp, const int relu, uint8_t* smem, int bid,
                           int nb) {
  uint8_t* sA = smem;
  uint8_t* sB = smem + 16384;
  float* scb = reinterpret_cast<float*>(smem + 32768);   // 128 f32
  float* ws_s = reinterpret_cast<float*>(smem + 33280);  // 32 f32
  const int tid = threadIdx.x;
  const int wv = tid >> 6, lane = tid & 63;
  const int quad = lane >> 4, l16 = lane & 15;
  const int wm = wv >> 1, wn = wv & 1;
  const int swc = (tid & 7) ^ ((tid >> 3) & 7);

  for (int b = bid; b < 1024; b += nb) {
    const int n0 = (b & 31) * 128, m0 = (b >> 5) * 128;
    if (tid < 32) ws_s[tid] = ws[tid * 32 + (b & 31)];

    const uint8_t* gA = qa + (size_t)(m0 + (tid >> 3)) * H + swc * 16;
    const uint8_t* gB = wt + (size_t)(n0 + (tid >> 3)) * H + swc * 16;
    const uint8_t* gS = (const uint8_t*)sxT + (size_t)m0 * 4 + lane * 16;
    uint8_t* lA = sA + wv * 1024;
    uint8_t* lB = sB + wv * 1024;

    int offp[2];
#pragma unroll
    for (int ksp = 0; ksp < 2; ++ksp)
      offp[ksp] = (((quad * 2 + ksp) ^ (l16 & 7)) << 4);
    const int arow = (wm * 64 + l16) * 128;
    const int brow = (wn * 64 + l16) * 128;
    const int scoff = wm * 64 + quad * 4;

    const v4f zf = {0.f, 0.f, 0.f, 0.f};
    v4f acc[4][4];
#pragma unroll
    for (int i = 0; i < 4; ++i)
#pragma unroll
      for (int j = 0; j < 4; ++j) acc[i][j] = zf;

    for (int kb = 0; kb < 32; ++kb) {
#pragma unroll
      for (int i = 0; i < 4; ++i) {
        gload16(gA + (size_t)i * (32 * H), lA + i * 4096);
        gload16(gB + (size_t)i * (32 * H), lB + i * 4096);
      }
      if (wv == 0 && lane < 32) gload16(gS + (size_t)kb * 16384, (uint8_t*)scb);
      gA += 128;
      gB += 128;
      __syncthreads();

      const float wsk = ws_s[kb];
      v2l bf[4][2];
#pragma unroll
      for (int tc = 0; tc < 4; ++tc)
#pragma unroll
        for (int ksp = 0; ksp < 2; ++ksp)
          bf[tc][ksp] = *(const v2l*)(sB + brow + tc * 2048 + offp[ksp]);

#pragma unroll
      for (int tr = 0; tr < 4; ++tr) {
        const v2l a0 = *(const v2l*)(sA + arow + tr * 2048 + offp[0]);
        const v2l a1 = *(const v2l*)(sA + arow + tr * 2048 + offp[1]);
        const v4f s4 = *(const v4f*)(scb + scoff + tr * 16) * wsk;
#pragma unroll
        for (int tc = 0; tc < 4; ++tc) {
          v4f p = __builtin_amdgcn_mfma_f32_16x16x32_fp8_fp8(a0.x, bf[tc][0].x, zf, 0, 0, 0);
          p = __builtin_amdgcn_mfma_f32_16x16x32_fp8_fp8(a0.y, bf[tc][0].y, p, 0, 0, 0);
          p = __builtin_amdgcn_mfma_f32_16x16x32_fp8_fp8(a1.x, bf[tc][1].x, p, 0, 0, 0);
          p = __builtin_amdgcn_mfma_f32_16x16x32_fp8_fp8(a1.y, bf[tc][1].y, p, 0, 0, 0);
          acc[tr][tc] += p * s4;
        }
      }
      __syncthreads();
    }

    const int mB = m0 + wm * 64 + quad * 4;
    const int nB = n0 + wn * 64 + l16;
#pragma unroll
    for (int tr = 0; tr < 4; ++tr) {
#pragma unroll
      for (int r = 0; r < 4; ++r) {
        const size_t rowOff = (size_t)(mB + tr * 16 + r) * H;
#pragma unroll
        for (int tc = 0; tc < 4; ++tc) {
          const size_t idx = rowOff + nB + tc * 16;
          float rv = resid[idx];
          if (relu) rv = fmaxf(rv, 0.f);
          outp[idx] = acc[tr][tc][r] + rv;
        }
      }
    }
  }
}

// ================= fused cooperative kernel ===============================
__global__ __launch_bounds__(256, 4) void mega_kernel(
    const float* x, const float* w0, const float* ws0, const float* w1,
    const float* ws1, const float* w2, const float* ws2, const float* nw0,
    const float* nw1, const float* nw2, const float* nw3, float* R,
    uint8_t* wq0, uint8_t* wq1, uint8_t* wq2, uint8_t* qa, float* sa) {
  __shared__ __attribute__((aligned(16))) uint8_t smem[33792];
  cg::grid_group grid = cg::this_grid();
  const int bid = blockIdx.x, nb = gridDim.x;

  // conv (weights) and quant0 (x) are independent: same stage, no grid sync
  conv_stage(w0, w1, w2, wq0, wq1, wq2, smem, bid, nb);
  quant_stage(x, nw0, qa, sa, 1, smem, bid, nb);
  grid.sync();
  gemm_stage(qa, sa, wq0, ws0, x, R, 1, smem, bid, nb);
  grid.sync();
  quant_stage(R, nw1, qa, sa, 0, smem, bid, nb);
  grid.sync();
  gemm_stage(qa, sa, wq1, ws1, R, R, 0, smem, bid, nb);
  grid.sync();
  quant_stage(R, nw2, qa, sa, 0, smem, bid, nb);
  grid.sync();
  gemm_stage(qa, sa, wq2, ws2, R, R, 0, smem, bid, nb);
  grid.sync();
  norm_stage(R, nw3, smem, bid, nb);
}

// ================= standalone kernels (fallback path, known-good 686us) ===
__global__ __launch_bounds__(256) void conv_w_kernel(
    const float* __restrict__ w0, const float* __restrict__ w1,
    const float* __restrict__ w2, uint8_t* __restrict__ o0,
    uint8_t* __restrict__ o1, uint8_t* __restrict__ o2) {
  __shared__ __attribute__((aligned(16))) uint8_t smem[8704];
  const int g = (blockIdx.z << 11) | (blockIdx.y << 6) | blockIdx.x;
  conv_stage(w0, w1, w2, o0, o1, o2, smem, g, 6144);
}

__global__ __launch_bounds__(256) void quant_kernel(const float* in,
                                                    const float* __restrict__ nw,
                                                    uint8_t* __restrict__ q,
                                                    float* __restrict__ sxT,
                                                    const int relu) {
  __shared__ __attribute__((aligned(16))) uint8_t smem[16];
  quant_stage(in, nw, q, sxT, relu, smem, blockIdx.x, 4096);
}

__global__ __launch_bounds__(256) void norm_kernel(float* io,
                                                   const float* __restrict__ nw) {
  __shared__ __attribute__((aligned(16))) uint8_t smem[16];
  norm_stage(io, nw, smem, blockIdx.x, 4096);
}

__global__ __launch_bounds__(256, 4) void gemm_kernel(
    const uint8_t* __restrict__ qa, const float* __restrict__ sxT,
    const uint8_t* __restrict__ wt, const float* __restrict__ ws,
    const float* resid, float* outp, const int relu) {
  __shared__ __attribute__((aligned(16))) uint8_t smem[33792];
  gemm_stage(qa, sxT, wt, ws, resid, outp, relu, smem,
             blockIdx.y * 32 + blockIdx.x, 1024);
}

extern "C" void kernel_launch(void* const* d_in, const int* in_sizes, int n_in,
                              void* d_out, int out_size, void* d_ws,
                              size_t ws_size, hipStream_t stream) {
  const float* x   = (const float*)d_in[0];
  const float* w0  = (const float*)d_in[1];
  const float* ws0 = (const float*)d_in[2];
  const float* w1  = (const float*)d_in[3];
  const float* ws1 = (const float*)d_in[4];
  const float* w2  = (const float*)d_in[5];
  const float* ws2 = (const float*)d_in[6];
  const float* nw0 = (const float*)d_in[7];
  const float* nw1 = (const float*)d_in[8];
  const float* nw2 = (const float*)d_in[9];
  const float* nw3 = (const float*)d_in[10];
  float* R = (float*)d_out;  // residual lives in d_out (in-place)

  uint8_t* base = (uint8_t*)d_ws;
  uint8_t* wq0 = base;
  uint8_t* wq1 = base + ((size_t)16 << 20);
  uint8_t* wq2 = base + ((size_t)32 << 20);
  uint8_t* qa  = base + ((size_t)48 << 20);
  float* sa    = (float*)(base + ((size_t)64 << 20));  // sxT[32][4096]

  static int grid_blocks = -1;
  if (grid_blocks < 0) {
    int per_cu = 0;
    if (hipOccupancyMaxActiveBlocksPerMultiprocessor(
            &per_cu, (const void*)mega_kernel, 256, 0) != hipSuccess ||
        per_cu < 1)
      per_cu = 0;
    long long mb = (long long)per_cu * 256;  // 256 CUs on MI355X
    grid_blocks = (int)(mb > 1024 ? 1024 : mb);
  }

  bool ok = false;
  if (grid_blocks >= 256) {  // need a sane co-resident grid for the stages
    void* args[] = {(void*)&x,   (void*)&w0,  (void*)&ws0, (void*)&w1,
                    (void*)&ws1, (void*)&w2,  (void*)&ws2, (void*)&nw0,
                    (void*)&nw1, (void*)&nw2, (void*)&nw3, (void*)&R,
                    (void*)&wq0, (void*)&wq1, (void*)&wq2, (void*)&qa,
                    (void*)&sa};
    ok = hipLaunchCooperativeKernel((const void*)mega_kernel,
                                    dim3(grid_blocks), dim3(256), args, 0,
                                    stream) == hipSuccess;
  }
  if (!ok) {
    // fallback: known-good separate-launch path (measured 686 us)
    conv_w_kernel<<<dim3(64, 32, 3), 256, 0, stream>>>(w0, w1, w2, wq0, wq1, wq2);
    quant_kernel<<<4096, 256, 0, stream>>>(x, nw0, qa, sa, 1);
    gemm_kernel<<<dim3(32, 32), 256, 0, stream>>>(qa, sa, wq0, ws0, x, R, 1);
    quant_kernel<<<4096, 256, 0, stream>>>(R, nw1, qa, sa, 0);
    gemm_kernel<<<dim3(32, 32), 256, 0, stream>>>(qa, sa, wq1, ws1, R, R, 0);
    quant_kernel<<<4096, 256, 0, stream>>>(R, nw2, qa, sa, 0);
    gemm_kernel<<<dim3(32, 32), 256, 0, stream>>>(qa, sa, wq2, ws2, R, R, 0);
    norm_kernel<<<4096, 256, 0, stream>>>(R, nw3);
  }
}

// Round 9
// 1454.293 us; speedup vs baseline: 1.1487x; 1.1487x over previous
//
#include <hip/hip_runtime.h>
#include <stdint.h>

#define H 4096

typedef float v4f __attribute__((ext_vector_type(4)));
typedef long long v2l __attribute__((ext_vector_type(2)));

__device__ __forceinline__ void gload16(const uint8_t* g, uint8_t* l) {
  __builtin_amdgcn_global_load_lds(
      (const __attribute__((address_space(1))) uint8_t*)g,
      (__attribute__((address_space(3))) uint8_t*)l, 16, 0, 0);
}

// permuted byte position within a 128-B k-block: orig b = ks*32 + q*8 + j
// stored at q*32 + ks*8 + j  (lane's (q,ks),(q,ks+1) frags contiguous 16B)
__device__ __forceinline__ int permpos(int kg) {
  const int kb = kg >> 7, b = kg & 127;
  const int ks = b >> 5, q = (b >> 3) & 3, j = b & 7;
  return kb * 128 + q * 32 + ks * 8 + j;
}

// ---- one conv tile: fp32 [k][n] -> fp8 transposed+permuted [n][perm(k)] ----
__device__ __forceinline__ void conv_tile(const float* __restrict__ w,
                                          uint8_t* __restrict__ o, int k0,
                                          int n0, uint8_t* smem) {
  uint8_t(*t)[136] = reinterpret_cast<uint8_t(*)[136]>(smem);
  const int tid = threadIdx.x;
  const int rr = tid >> 4, cc = (tid & 15) * 4;
#pragma unroll
  for (int j = 0; j < 8; ++j) {
    const int r = rr + j * 16;
    v4f f = *(const v4f*)(w + (size_t)(k0 + r) * H + n0 + cc);
    unsigned p = __builtin_amdgcn_cvt_pk_fp8_f32(f.x, f.y, 0, false);
    p = __builtin_amdgcn_cvt_pk_fp8_f32(f.z, f.w, p, true);
    t[cc + 0][r] = p & 0xff;
    t[cc + 1][r] = (p >> 8) & 0xff;
    t[cc + 2][r] = (p >> 16) & 0xff;
    t[cc + 3][r] = p >> 24;
  }
  __syncthreads();
#pragma unroll
  for (int i = 0; i < 2; ++i) {
    const int c = i * 256 + tid;
    const int n = c >> 3, o16 = c & 7, q = o16 >> 1, h = o16 & 1;
    long long lo = *(const long long*)&t[n][64 * h + q * 8];
    long long hi = *(const long long*)&t[n][64 * h + 32 + q * 8];
    v2l val;
    val.x = lo;
    val.y = hi;
    *(v2l*)(o + (size_t)(n0 + n) * H + k0 + o16 * 16) = val;
  }
}

// ---- one row: (optional relu) + rmsnorm + group-128 fp8 quant (256 thr) ----
// bit-identical to the proven quant_kernel body
__device__ __forceinline__ void quant_row(const float* in,
                                          const float* __restrict__ nw,
                                          uint8_t* q, float* sxT, int row,
                                          int relu, float* red) {
  const int tid = threadIdx.x;
  const v4f* rp = (const v4f*)(in + (size_t)row * H);
  v4f v[4];
  float ss = 0.f;
#pragma unroll
  for (int j = 0; j < 4; ++j) {
    v4f x = rp[j * 256 + tid];
    if (relu) {
      x.x = fmaxf(x.x, 0.f); x.y = fmaxf(x.y, 0.f);
      x.z = fmaxf(x.z, 0.f); x.w = fmaxf(x.w, 0.f);
    }
    v[j] = x;
    ss += x.x * x.x + x.y * x.y + x.z * x.z + x.w * x.w;
  }
#pragma unroll
  for (int o = 32; o > 0; o >>= 1) ss += __shfl_down(ss, o);
  if ((tid & 63) == 0) red[tid >> 6] = ss;
  __syncthreads();
  ss = red[0] + red[1] + red[2] + red[3];
  const float rinv = 1.f / sqrtf(ss * (1.f / H) + 1e-6f);
#pragma unroll
  for (int j = 0; j < 4; ++j) {
    v4f nv = ((const v4f*)nw)[j * 256 + tid];
    v4f y;
    y.x = v[j].x * rinv * nv.x;
    y.y = v[j].y * rinv * nv.y;
    y.z = v[j].z * rinv * nv.z;
    y.w = v[j].w * rinv * nv.w;
    float am =
        fmaxf(fmaxf(fabsf(y.x), fabsf(y.y)), fmaxf(fabsf(y.z), fabsf(y.w)));
#pragma unroll
    for (int o = 16; o > 0; o >>= 1) am = fmaxf(am, __shfl_xor(am, o, 32));
    const float s = fmaxf(am, 1e-12f) / 448.f;  // true div: bit-exact vs ref
    unsigned p = __builtin_amdgcn_cvt_pk_fp8_f32(y.x / s, y.y / s, 0, false);
    p = __builtin_amdgcn_cvt_pk_fp8_f32(y.z / s, y.w / s, p, true);
    const int col = (j * 256 + tid) * 4;
    *(unsigned*)(q + (size_t)row * H + permpos(col)) = p;
    if ((tid & 31) == 0)
      sxT[(size_t)(j * 8 + (tid >> 5)) * 4096 + row] = s;
  }
}

// ---- one row: final rmsnorm in-place (256 thr) ----
__device__ __forceinline__ void norm_row(float* io, const float* __restrict__ nw,
                                         int row, float* red) {
  const int tid = threadIdx.x;
  v4f* rp = (v4f*)(io + (size_t)row * H);
  v4f v[4];
  float ss = 0.f;
#pragma unroll
  for (int j = 0; j < 4; ++j) {
    v4f x = rp[j * 256 + tid];
    v[j] = x;
    ss += x.x * x.x + x.y * x.y + x.z * x.z + x.w * x.w;
  }
#pragma unroll
  for (int o = 32; o > 0; o >>= 1) ss += __shfl_down(ss, o);
  if ((tid & 63) == 0) red[tid >> 6] = ss;
  __syncthreads();
  ss = red[0] + red[1] + red[2] + red[3];
  const float rinv = 1.f / sqrtf(ss * (1.f / H) + 1e-6f);
#pragma unroll
  for (int j = 0; j < 4; ++j) {
    v4f nv = ((const v4f*)nw)[j * 256 + tid];
    v4f y;
    y.x = v[j].x * rinv * nv.x;
    y.y = v[j].y * rinv * nv.y;
    y.z = v[j].z * rinv * nv.z;
    y.w = v[j].w * rinv * nv.w;
    rp[j * 256 + tid] = y;
  }
}

// ---- launch 1: conv (6144 tiles) || quant0 (4096 rows); block 0 zeroes sync
__global__ __launch_bounds__(256) void prep_kernel(
    const float* __restrict__ w0, const float* __restrict__ w1,
    const float* __restrict__ w2, uint8_t* __restrict__ o0,
    uint8_t* __restrict__ o1, uint8_t* __restrict__ o2, const float* x,
    const float* __restrict__ nw0, uint8_t* qa, float* sa, int* sync0) {
  __shared__ __attribute__((aligned(16))) uint8_t smem[8704];
  const int bid = blockIdx.x;
  if (bid == 0) {  // zero the 3 layers' panel counters (graph replays too)
    for (int i = threadIdx.x; i < 3072; i += 256) sync0[i] = 0;
  }
  if (bid < 6144) {
    const int z = bid >> 11, rem = bid & 2047;
    const float* w = (z == 0) ? w0 : (z == 1 ? w1 : w2);
    uint8_t* o = (z == 0) ? o0 : (z == 1 ? o1 : o2);
    conv_tile(w, o, (rem >> 6) * 128, (rem & 63) * 64, smem);
  } else {
    quant_row(x, nw0, qa, sa, bid - 6144, 1, (float*)smem);
  }
}

// ---- fused GEMM + panel-synced tail (quant or final norm) ----
// GEMM body = R0 structure verbatim (133us, MfmaUtil 42%).
// Tail via FINISH RANK within the block's own m-panel: atomicAdd(&cnt[p])
// returns rank 0..31. Ranks 0..15 exit (free slots). Ranks 16..31 process 8
// fixed rows of panel p; only ranks 16..30 spin until cnt[p]==32 (rank 31
// already knows). DEADLOCK-PROOF under partial residency: spinners <= 15 per
// panel (480 total) < residency even at half the chip; all other blocks
// terminate and free slots, so unscheduled producers always get scheduled.
// [R8 bug: global work-queue let ALL 1024 blocks spin -> hang.]
// Panel-locality: GEMM reads of qa/sxT/resid touch only rows m0..m0+127, so
// overwriting qa/sa for a COMPLETED panel while others compute is race-free.
__global__ __launch_bounds__(256, 4) void gemm_fused_kernel(
    const uint8_t* qa,                // [M][perm(K)] fp8 activations (in)
    const float* sxT,                 // [32][M] act scales (in)
    const uint8_t* __restrict__ wt,   // [N][perm(K)] fp8 weight
    const float* __restrict__ ws,     // [32][32] weight scales [kb][nb]
    const float* resid, float* outp, const int relu,
    int* cnt,                         // [32] per-panel completion counters
    const int tailmode,               // 0 = quant tail, 1 = norm tail
    uint8_t* qa2, float* sa2, const float* __restrict__ nwt) {
  __shared__ __attribute__((aligned(16))) uint8_t smem[33792];
  uint8_t* sA = smem;
  uint8_t* sB = smem + 16384;
  float* scb = reinterpret_cast<float*>(smem + 32768);
  float* ws_s = reinterpret_cast<float*>(smem + 33280);

  const int tid = threadIdx.x;
  const int n0 = blockIdx.x * 128, m0 = blockIdx.y * 128;
  if (tid < 32) ws_s[tid] = ws[tid * 32 + blockIdx.x];

  const int wv = tid >> 6, lane = tid & 63;
  const int quad = lane >> 4, l16 = lane & 15;
  const int wm = wv >> 1, wn = wv & 1;

  const int swc = (tid & 7) ^ ((tid >> 3) & 7);
  const uint8_t* gA = qa + (size_t)(m0 + (tid >> 3)) * H + swc * 16;
  const uint8_t* gB = wt + (size_t)(n0 + (tid >> 3)) * H + swc * 16;
  const uint8_t* gS = (const uint8_t*)sxT + (size_t)m0 * 4 + lane * 16;
  uint8_t* lA = sA + wv * 1024;
  uint8_t* lB = sB + wv * 1024;

  int offp[2];
#pragma unroll
  for (int ksp = 0; ksp < 2; ++ksp)
    offp[ksp] = (((quad * 2 + ksp) ^ (l16 & 7)) << 4);
  const int arow = (wm * 64 + l16) * 128;
  const int brow = (wn * 64 + l16) * 128;
  const int scoff = wm * 64 + quad * 4;

  const v4f zf = {0.f, 0.f, 0.f, 0.f};
  v4f acc[4][4];
#pragma unroll
  for (int i = 0; i < 4; ++i)
#pragma unroll
    for (int j = 0; j < 4; ++j) acc[i][j] = zf;

  for (int kb = 0; kb < 32; ++kb) {
#pragma unroll
    for (int i = 0; i < 4; ++i) {
      gload16(gA + (size_t)i * (32 * H), lA + i * 4096);
      gload16(gB + (size_t)i * (32 * H), lB + i * 4096);
    }
    if (wv == 0 && lane < 32) gload16(gS + (size_t)kb * 16384, (uint8_t*)scb);
    gA += 128;
    gB += 128;
    __syncthreads();

    const float wsk = ws_s[kb];
    v2l bf[4][2];
#pragma unroll
    for (int tc = 0; tc < 4; ++tc)
#pragma unroll
      for (int ksp = 0; ksp < 2; ++ksp)
        bf[tc][ksp] = *(const v2l*)(sB + brow + tc * 2048 + offp[ksp]);

#pragma unroll
    for (int tr = 0; tr < 4; ++tr) {
      const v2l a0 = *(const v2l*)(sA + arow + tr * 2048 + offp[0]);
      const v2l a1 = *(const v2l*)(sA + arow + tr * 2048 + offp[1]);
      const v4f s4 = *(const v4f*)(scb + scoff + tr * 16) * wsk;
#pragma unroll
      for (int tc = 0; tc < 4; ++tc) {
        v4f p = __builtin_amdgcn_mfma_f32_16x16x32_fp8_fp8(a0.x, bf[tc][0].x, zf, 0, 0, 0);
        p = __builtin_amdgcn_mfma_f32_16x16x32_fp8_fp8(a0.y, bf[tc][0].y, p, 0, 0, 0);
        p = __builtin_amdgcn_mfma_f32_16x16x32_fp8_fp8(a1.x, bf[tc][1].x, p, 0, 0, 0);
        p = __builtin_amdgcn_mfma_f32_16x16x32_fp8_fp8(a1.y, bf[tc][1].y, p, 0, 0, 0);
        acc[tr][tc] += p * s4;
      }
    }
    __syncthreads();
  }

  // epilogue: add residual (relu(x) for layer 0)
  const int mB = m0 + wm * 64 + quad * 4;
  const int nB = n0 + wn * 64 + l16;
#pragma unroll
  for (int tr = 0; tr < 4; ++tr) {
#pragma unroll
    for (int r = 0; r < 4; ++r) {
      const size_t rowOff = (size_t)(mB + tr * 16 + r) * H;
#pragma unroll
      for (int tc = 0; tc < 4; ++tc) {
        const size_t idx = rowOff + nB + tc * 16;
        float rv = resid[idx];
        if (relu) rv = fmaxf(rv, 0.f);
        outp[idx] = acc[tr][tc][r] + rv;
      }
    }
  }

  // ---- release this block's panel contribution, learn finish rank ----
  __threadfence();  // release: outp panel writes device-visible
  __shared__ int rank_s;
  if (tid == 0) rank_s = atomicAdd(&cnt[m0 >> 7], 1);
  __syncthreads();
  const int rank = rank_s;
  if (rank < 16) return;  // free the slot

  if (rank < 31) {  // ranks 16..30: wait for own panel (bounded spinners)
    if (tid == 0) {
      while (__hip_atomic_load(&cnt[m0 >> 7], __ATOMIC_ACQUIRE,
                               __HIP_MEMORY_SCOPE_AGENT) < 32)
        __builtin_amdgcn_s_sleep(8);
    }
    __syncthreads();
  }
  __threadfence();  // acquire: no stale reads of other blocks' outp writes

  float* red = scb;  // reuse LDS (scb dead after K-loop)
  const int rb = m0 + (rank - 16) * 8;
  for (int r = rb; r < rb + 8; ++r) {
    if (tailmode == 0)
      quant_row(outp, nwt, qa2, sa2, r, 0, red);
    else
      norm_row(outp, nwt, r, red);
    __syncthreads();  // red WAR between rows
  }
}

extern "C" void kernel_launch(void* const* d_in, const int* in_sizes, int n_in,
                              void* d_out, int out_size, void* d_ws,
                              size_t ws_size, hipStream_t stream) {
  const float* x   = (const float*)d_in[0];
  const float* w0  = (const float*)d_in[1];
  const float* ws0 = (const float*)d_in[2];
  const float* w1  = (const float*)d_in[3];
  const float* ws1 = (const float*)d_in[4];
  const float* w2  = (const float*)d_in[5];
  const float* ws2 = (const float*)d_in[6];
  const float* nw0 = (const float*)d_in[7];
  const float* nw1 = (const float*)d_in[8];
  const float* nw2 = (const float*)d_in[9];
  const float* nw3 = (const float*)d_in[10];
  float* R = (float*)d_out;  // residual lives in d_out (in-place)

  uint8_t* base = (uint8_t*)d_ws;
  uint8_t* wq0 = base;
  uint8_t* wq1 = base + ((size_t)16 << 20);
  uint8_t* wq2 = base + ((size_t)32 << 20);
  uint8_t* qa  = base + ((size_t)48 << 20);
  float* sa    = (float*)(base + ((size_t)64 << 20));  // sxT[32][4096]
  int* sync0   = (int*)(base + ((size_t)65 << 20));    // 3 x 1024 ints

  prep_kernel<<<10240, 256, 0, stream>>>(w0, w1, w2, wq0, wq1, wq2, x, nw0, qa,
                                         sa, sync0);

  int* c0 = sync0;
  int* c1 = sync0 + 1024;
  int* c2 = sync0 + 2048;
  // layer 0: gemm + quant1 tail (rewrites qa/sa for layer 1)
  gemm_fused_kernel<<<dim3(32, 32), 256, 0, stream>>>(
      qa, sa, wq0, ws0, x, R, 1, c0, 0, qa, sa, nw1);
  // layer 1: gemm + quant2 tail
  gemm_fused_kernel<<<dim3(32, 32), 256, 0, stream>>>(
      qa, sa, wq1, ws1, R, R, 0, c1, 0, qa, sa, nw2);
  // layer 2: gemm + final-norm tail
  gemm_fused_kernel<<<dim3(32, 32), 256, 0, stream>>>(
      qa, sa, wq2, ws2, R, R, 0, c2, 1, qa, sa, nw3);
}